// Round 6
// baseline (613.496 us; speedup 1.0000x reference)
//
#include <hip/hip_runtime.h>
#include <hip/hip_bf16.h>
#include <cstdint>

typedef __bf16 bf16;
typedef __bf16 bf16x4 __attribute__((ext_vector_type(4)));
typedef __bf16 bf16x8 __attribute__((ext_vector_type(8)));
typedef float f32x4 __attribute__((ext_vector_type(4)));

#define GK 768   // inner K for both GEMMs
#define LN_EPS 1e-5f
#define NORM_EPS 1e-12f

// ---------------- async global->LDS helper ----------------
__device__ __forceinline__ void gl_lds16(const void* g, void* l) {
  __builtin_amdgcn_global_load_lds(
      (__attribute__((address_space(1))) uint32_t*)(uintptr_t)g,
      (__attribute__((address_space(3))) uint32_t*)(uintptr_t)l,
      16, 0, 0);
}

// ---------------- block reduce (2 values, 3 waves / 192 threads) ----------------
__device__ __forceinline__ void blockReduce2w3(float& s, float& ss, float* sm) {
  #pragma unroll
  for (int o = 32; o > 0; o >>= 1) {
    s  += __shfl_down(s, o, 64);
    ss += __shfl_down(ss, o, 64);
  }
  int wave = threadIdx.x >> 6, lane = threadIdx.x & 63;
  if (lane == 0) { sm[wave] = s; sm[3 + wave] = ss; }
  __syncthreads();
  s  = sm[0] + sm[1] + sm[2];
  ss = sm[3] + sm[4] + sm[5];
  __syncthreads();
}

// ---------------- 0: tiled transpose + fp32->bf16 ----------------
__global__ __launch_bounds__(256) void transpose_cvt(const float* __restrict__ w,
                                                     bf16* __restrict__ wt,
                                                     int R, int Ncols) {
  __shared__ float tile[32][33];
  int tx = threadIdx.x & 31, ty = threadIdx.x >> 5;
  int c0 = blockIdx.x * 32, r0 = blockIdx.y * 32;
  #pragma unroll
  for (int i = 0; i < 32; i += 8)
    tile[ty + i][tx] = w[(size_t)(r0 + ty + i) * Ncols + (c0 + tx)];
  __syncthreads();
  #pragma unroll
  for (int i = 0; i < 32; i += 8)
    wt[(size_t)(c0 + ty + i) * R + (r0 + tx)] = (bf16)tile[tx][ty + i];
}

// ---------------- 1: input LayerNorm -> bf16 (192 threads) ----------
__global__ __launch_bounds__(192) void ln_in_kernel(const float* __restrict__ x,
                                                    const float* __restrict__ g,
                                                    const float* __restrict__ b,
                                                    bf16* __restrict__ h) {
  __shared__ float sm[6];
  int row = blockIdx.x, t = threadIdx.x;
  const float* xr = x + (size_t)row * 768;
  float4 v = ((const float4*)xr)[t];
  float s  = v.x + v.y + v.z + v.w;
  float ss = v.x * v.x + v.y * v.y + v.z * v.z + v.w * v.w;
  blockReduce2w3(s, ss, sm);
  float mu  = s * (1.0f / 768.0f);
  float inv = rsqrtf(ss * (1.0f / 768.0f) - mu * mu + LN_EPS);
  float4 gg = ((const float4*)g)[t];
  float4 bb = ((const float4*)b)[t];
  bf16x4 o;
  o[0] = (bf16)((v.x - mu) * inv * gg.x + bb.x);
  o[1] = (bf16)((v.y - mu) * inv * gg.y + bb.y);
  o[2] = (bf16)((v.z - mu) * inv * gg.z + bb.z);
  o[3] = (bf16)((v.w - mu) * inv * gg.w + bb.w);
  ((bf16x4*)(h + (size_t)row * 768))[t] = o;
}

// ================= 256x256 pipelined 8-phase bf16 GEMM (16x16x32) ==========
// Reads for phase p+1 are issued inside phase p's MFMA window (register-level
// pipeline). Frag sets: a0s (A mh0), a1s (A mh1), b0s (B n01), b1s (B n23);
// each is refilled exactly one phase after its last use -> no double-buffer.
// One barrier per phase. vmcnt slots at ph2(4)/ph3(2)/ph6(4)/ph7(2).
// T2 swizzle: XOR byte-bits 4-6 with row-bits 0-2, involution on both sides.

#define SWZ(x) ((x) ^ ((((x) >> 7) & 7) << 4))

#define SB0 __builtin_amdgcn_sched_barrier(0)
#define BARS do { SB0; __builtin_amdgcn_s_barrier(); SB0; } while (0)
#define LGKM0 do { asm volatile("s_waitcnt lgkmcnt(0)" ::: "memory"); SB0; } while (0)
#define VMC(n) do { SB0; asm volatile("s_waitcnt vmcnt(" #n ")" ::: "memory"); } while (0)
#define PRIO1 __builtin_amdgcn_s_setprio(1)
#define PRIO0 __builtin_amdgcn_s_setprio(0)

#define LDA_(S, i, ks, base, mh) \
  S[i][ks] = *(const bf16x8*)((base) + SWZ((wm * 128 + (mh) * 64 + (i) * 16 + llo) * 128 + (ks) * 64 + lhi * 16))
#define RD_A(S, base, mh) do { \
  LDA_(S, 0, 0, base, mh); LDA_(S, 1, 0, base, mh); LDA_(S, 2, 0, base, mh); LDA_(S, 3, 0, base, mh); \
  LDA_(S, 0, 1, base, mh); LDA_(S, 1, 1, base, mh); LDA_(S, 2, 1, base, mh); LDA_(S, 3, 1, base, mh); } while (0)

#define LDB_(S, jn, ks, base, nh) \
  S[jn][ks] = *(const bf16x8*)((base) + SWZ(((nh) * 128 + wn * 32 + (jn) * 16 + llo) * 128 + (ks) * 64 + lhi * 16))
#define RD_B(S, base, nh) do { \
  LDB_(S, 0, 0, base, nh); LDB_(S, 1, 0, base, nh); LDB_(S, 0, 1, base, nh); LDB_(S, 1, 1, base, nh); } while (0)

#define MF1v(AS, BS, mh, nh, i, jn, ks) \
  acc[(mh) * 4 + (i)][(nh) * 2 + (jn)] = __builtin_amdgcn_mfma_f32_16x16x32_bf16( \
      AS[i][ks], BS[jn][ks], acc[(mh) * 4 + (i)][(nh) * 2 + (jn)], 0, 0, 0)
#define MF16(AS, BS, mh, nh) do { PRIO1; \
  MF1v(AS, BS, mh, nh, 0, 0, 0); MF1v(AS, BS, mh, nh, 0, 1, 0); \
  MF1v(AS, BS, mh, nh, 1, 0, 0); MF1v(AS, BS, mh, nh, 1, 1, 0); \
  MF1v(AS, BS, mh, nh, 2, 0, 0); MF1v(AS, BS, mh, nh, 2, 1, 0); \
  MF1v(AS, BS, mh, nh, 3, 0, 0); MF1v(AS, BS, mh, nh, 3, 1, 0); \
  MF1v(AS, BS, mh, nh, 0, 0, 1); MF1v(AS, BS, mh, nh, 0, 1, 1); \
  MF1v(AS, BS, mh, nh, 1, 0, 1); MF1v(AS, BS, mh, nh, 1, 1, 1); \
  MF1v(AS, BS, mh, nh, 2, 0, 1); MF1v(AS, BS, mh, nh, 2, 1, 1); \
  MF1v(AS, BS, mh, nh, 3, 0, 1); MF1v(AS, BS, mh, nh, 3, 1, 1); \
  PRIO0; } while (0)

#define STA(b, q, kt) gl_lds16(A + srcA[q] + (kt) * 64, &As_[b][(q) * 4096 + wave * 512])
#define STB(b, q, kt) gl_lds16(Bt + srcB[q] + (kt) * 64, &Bs_[b][(q) * 4096 + wave * 512])

template <bool OUT_BF16>
__global__ __launch_bounds__(512, 2) void gemm8p(const bf16* __restrict__ A,
                                                 const bf16* __restrict__ Bt,
                                                 void* __restrict__ Cv,
                                                 int Nn, int NBN) {
  __shared__ __align__(16) bf16 As_[2][16384];
  __shared__ __align__(16) bf16 Bs_[2][16384];
  const int tid = threadIdx.x;
  const int wave = tid >> 6, lane = tid & 63;
  const int llo = lane & 15, lhi = lane >> 4;
  const int wm = wave >> 2, wn = wave & 3;

  const int nwg = gridDim.x, bid = blockIdx.x;
  const int wg = (bid & 7) * (nwg >> 3) + (bid >> 3);
  const int rb = wg / NBN, cb = wg - rb * NBN;
  const int brow = rb * 256, bcol = cb * 256;

  uint32_t srcA[4], srcB[4];
  #pragma unroll
  for (int q = 0; q < 4; ++q) {
    int d = q * 8192 + tid * 16;
    int a = SWZ(d);
    int r = a >> 7, c = (a & 127) >> 1;
    srcA[q] = (uint32_t)(brow + r) * GK + c;
    int nh = r >> 7, wnn = (r >> 5) & 3, r32 = r & 31;
    srcB[q] = (uint32_t)(bcol + wnn * 64 + nh * 32 + r32) * GK + c;
  }

  f32x4 acc[8][4];
  #pragma unroll
  for (int m = 0; m < 8; ++m)
    #pragma unroll
    for (int n = 0; n < 4; ++n) acc[m][n] = (f32x4){0.f, 0.f, 0.f, 0.f};

  bf16x8 a0s[4][2], a1s[4][2], b0s[2][2], b1s[2][2];
  const char* As0 = (const char*)&As_[0][0];
  const char* As1 = (const char*)&As_[1][0];
  const char* Bs0 = (const char*)&Bs_[0][0];
  const char* Bs1 = (const char*)&Bs_[1][0];

  // -------- prologue: tile0 full (8 chunks) + tile1's A0,A2,B0,B1
  STA(0, 0, 0); STA(0, 1, 0); STA(0, 2, 0); STA(0, 3, 0);
  STB(0, 0, 0); STB(0, 1, 0); STB(0, 2, 0); STB(0, 3, 0);
  STA(1, 0, 1); STA(1, 2, 1); STB(1, 0, 1); STB(1, 1, 1);
  SB0;
  asm volatile("s_waitcnt vmcnt(4)" ::: "memory");
  __builtin_amdgcn_s_barrier();
  SB0;
  // "window -1": frags for ph1 (A mh0, B n01 of tile 0)
  RD_A(a0s, As0, 0); RD_B(b0s, Bs0, 0);
  SB0;

  for (int j = 0; j < 6; ++j) {
    const int t1 = 2 * j + 1, t2 = 2 * j + 2, t3 = 2 * j + 3;
    // ---- ph1: window reads B-n23(even); MFMA a0*b0
    LGKM0;
    RD_B(b1s, Bs0, 1); SB0;
    STA(1, 1, t1); STA(1, 3, t1); SB0;
    MF16(a0s, b0s, 0, 0);
    BARS;
    // ---- ph2: window reads A-mh1(even); MFMA a0*b1; drain odd A0,A2,B0,B1
    LGKM0;
    RD_A(a1s, As0, 1); SB0;
    STB(1, 2, t1); STB(1, 3, t1); SB0;
    MF16(a0s, b1s, 0, 1);
    VMC(4);
    BARS;
    // ---- ph3: window reads A-mh0(odd); MFMA a1*b0; drain odd A1,A3,B2,B3
    LGKM0;
    RD_A(a0s, As1, 0); SB0;
    STA(0, 0, t2); STA(0, 2, t2); SB0;
    MF16(a1s, b0s, 1, 0);
    VMC(2);
    BARS;
    // ---- ph4: window reads B-n01(odd); MFMA a1*b1
    LGKM0;
    RD_B(b0s, Bs1, 0); SB0;
    STB(0, 0, t2); STB(0, 1, t2); SB0;
    MF16(a1s, b1s, 1, 1);
    BARS;
    // ---- ph5: window reads B-n23(odd); MFMA a0*b0
    LGKM0;
    RD_B(b1s, Bs1, 1); SB0;
    STA(0, 1, t2); STA(0, 3, t2); SB0;
    MF16(a0s, b0s, 0, 0);
    BARS;
    // ---- ph6: window reads A-mh1(odd); MFMA a0*b1; drain even A0,A2,B0,B1
    LGKM0;
    RD_A(a1s, As1, 1); SB0;
    STB(0, 2, t2); STB(0, 3, t2); SB0;
    MF16(a0s, b1s, 0, 1);
    VMC(4);
    BARS;
    // ---- ph7: window reads A-mh0(next even); MFMA a1*b0; drain even A1,A3,B2,B3
    LGKM0;
    RD_A(a0s, As0, 0); SB0;
    STA(1, 0, t3); STA(1, 2, t3); SB0;
    MF16(a1s, b0s, 1, 0);
    VMC(2);
    BARS;
    // ---- ph8: window reads B-n01(next even); MFMA a1*b1
    LGKM0;
    RD_B(b0s, Bs0, 0); SB0;
    STB(1, 0, t3); STB(1, 1, t3); SB0;
    MF16(a1s, b1s, 1, 1);
    BARS;
  }

  // -------- epilogue: C write
  #pragma unroll
  for (int m = 0; m < 8; ++m) {
    #pragma unroll
    for (int n = 0; n < 4; ++n) {
      int row = brow + wm * 128 + m * 16 + lhi * 4;
      int col = bcol + wn * 64 + n * 16 + llo;
      #pragma unroll
      for (int r2 = 0; r2 < 4; ++r2) {
        if (OUT_BF16)
          ((bf16*)Cv)[(size_t)(row + r2) * Nn + col] = (bf16)acc[m][n][r2];
        else
          ((float*)Cv)[(size_t)(row + r2) * Nn + col] = acc[m][n][r2];
      }
    }
  }
}

// ---------------- 3a: kv partial sums, k-norm computed inline ----------------
__global__ __launch_bounds__(256) void kv_partial(const bf16* __restrict__ qkv,
                                                  float* __restrict__ kvp) {
  __shared__ float sm[4][768];
  int b = blockIdx.x >> 5, chunk = blockIdx.x & 31;
  int wave = threadIdx.x >> 6, lane = threadIdx.x & 63;
  const bf16* base = qkv + ((size_t)(b * 4096 + chunk * 128 + wave * 32)) * 2304;
  float acc[3][4] = {};
  for (int i = 0; i < 32; ++i) {
    const bf16* kr = base + (size_t)i * 2304 + 768;
    const bf16* vr = kr + 768;
    bf16x4 k4[3], v4[3];
    #pragma unroll
    for (int c = 0; c < 3; ++c) {
      k4[c] = *(const bf16x4*)(kr + c * 256 + lane * 4);
      v4[c] = *(const bf16x4*)(vr + c * 256 + lane * 4);
    }
    float ssk = 0.f;
    #pragma unroll
    for (int c = 0; c < 3; ++c)
      #pragma unroll
      for (int j = 0; j < 4; ++j) { float kf = (float)k4[c][j]; ssk += kf * kf; }
    #pragma unroll
    for (int off = 32; off > 0; off >>= 1) ssk += __shfl_xor(ssk, off, 64);
    float wi = 1.0f / fmaxf(sqrtf(ssk), NORM_EPS);
    #pragma unroll
    for (int c = 0; c < 3; ++c)
      #pragma unroll
      for (int j = 0; j < 4; ++j)
        acc[c][j] += (float)k4[c][j] * (float)v4[c][j] * wi;
  }
  #pragma unroll
  for (int c = 0; c < 3; ++c)
    #pragma unroll
    for (int j = 0; j < 4; ++j)
      sm[wave][c * 256 + lane * 4 + j] = acc[c][j];
  __syncthreads();
  int t = threadIdx.x;
  #pragma unroll
  for (int c = 0; c < 3; ++c) {
    int e = c * 256 + t;
    kvp[(size_t)blockIdx.x * 768 + e] = sm[0][e] + sm[1][e] + sm[2][e] + sm[3][e];
  }
}

// ---------------- 3b: reduce 32 partials -> kv[8][768] ----------------
__global__ __launch_bounds__(256) void kv_reduce(const float* __restrict__ kvp,
                                                 float* __restrict__ kv) {
  int i = blockIdx.x * 256 + threadIdx.x;
  int b = i / 768, e = i - b * 768;
  float s = 0.f;
  #pragma unroll
  for (int c = 0; c < 32; ++c) s += kvp[(size_t)(b * 32 + c) * 768 + e];
  kv[i] = s;
}

// ---------------- 4: attn = phi_q * kv (q-norm inline), LN over E -> bf16 ----
__global__ __launch_bounds__(192) void attn_ln_kernel(const bf16* __restrict__ qkv,
                                                      const float* __restrict__ kv,
                                                      const float* __restrict__ g,
                                                      const float* __restrict__ b,
                                                      bf16* __restrict__ a) {
  __shared__ float sm[6];
  int row = blockIdx.x, t = threadIdx.x;
  int bt = row >> 12;
  const bf16* qr = qkv + (size_t)row * 2304;
  bf16x4 q4 = ((const bf16x4*)qr)[t];
  float q0 = (float)q4[0], q1 = (float)q4[1], q2 = (float)q4[2], q3 = (float)q4[3];
  float sq = q0 * q0 + q1 * q1 + q2 * q2 + q3 * q3, dummy = 0.f;
  blockReduce2w3(sq, dummy, sm);
  float iq = 1.0f / fmaxf(sqrtf(sq), NORM_EPS);
  float4 kv4 = ((const float4*)(kv + bt * 768))[t];
  float4 av;
  av.x = q0 * iq * kv4.x;
  av.y = q1 * iq * kv4.y;
  av.z = q2 * iq * kv4.z;
  av.w = q3 * iq * kv4.w;
  float s  = av.x + av.y + av.z + av.w;
  float ss = av.x * av.x + av.y * av.y + av.z * av.z + av.w * av.w;
  blockReduce2w3(s, ss, sm);
  float mu  = s * (1.0f / 768.0f);
  float inv = rsqrtf(ss * (1.0f / 768.0f) - mu * mu + LN_EPS);
  float4 gg = ((const float4*)g)[t];
  float4 bb = ((const float4*)b)[t];
  bf16x4 o;
  o[0] = (bf16)((av.x - mu) * inv * gg.x + bb.x);
  o[1] = (bf16)((av.y - mu) * inv * gg.y + bb.y);
  o[2] = (bf16)((av.z - mu) * inv * gg.z + bb.z);
  o[3] = (bf16)((av.w - mu) * inv * gg.w + bb.w);
  ((bf16x4*)(a + (size_t)row * 768))[t] = o;
}

// ---------------- launcher ----------------
extern "C" void kernel_launch(void* const* d_in, const int* in_sizes, int n_in,
                              void* d_out, int out_size, void* d_ws, size_t ws_size,
                              hipStream_t stream) {
  const float* x      = (const float*)d_in[0];
  const float* w_qkv  = (const float*)d_in[1];
  const float* w_proj = (const float*)d_in[2];
  const float* g_in   = (const float*)d_in[3];
  const float* b_in   = (const float*)d_in[4];
  const float* g_out  = (const float*)d_in[5];
  const float* b_out  = (const float*)d_in[6];

  char* ws = (char*)d_ws;
  bf16*  wqkvt  = (bf16*)(ws);                              // [2304][768] bf16
  bf16*  wprojt = (bf16*)(ws + 3538944);                    // [768][768]  bf16
  bf16*  h      = (bf16*)(ws + 4718592);                    // [32768][768] bf16 (reused as 'a')
  bf16*  qkv    = (bf16*)(ws + 55050240);                   // [32768][2304] bf16
  float* kvp    = (float*)(ws + 206045184);                 // [8*32][768]
  float* kv     = (float*)(ws + 206831616);                 // [8][768]

  transpose_cvt<<<dim3(2304 / 32, 768 / 32), 256, 0, stream>>>(w_qkv, wqkvt, 768, 2304);
  transpose_cvt<<<dim3(768 / 32, 768 / 32), 256, 0, stream>>>(w_proj, wprojt, 768, 768);
  ln_in_kernel<<<32768, 192, 0, stream>>>(x, g_in, b_in, h);
  gemm8p<true><<<128 * 9, 512, 0, stream>>>(h, wqkvt, (void*)qkv, 2304, 9);
  kv_partial<<<256, 256, 0, stream>>>(qkv, kvp);
  kv_reduce<<<24, 256, 0, stream>>>(kvp, kv);
  attn_ln_kernel<<<32768, 192, 0, stream>>>(qkv, kv, g_out, b_out, h);
  gemm8p<false><<<128 * 3, 512, 0, stream>>>(h, wprojt, d_out, 768, 3);
}

// Round 7
// 292.349 us; speedup vs baseline: 2.0985x; 2.0985x over previous
//
#include <hip/hip_runtime.h>
#include <hip/hip_bf16.h>
#include <cstdint>

typedef __bf16 bf16;
typedef __bf16 bf16x4 __attribute__((ext_vector_type(4)));
typedef __bf16 bf16x8 __attribute__((ext_vector_type(8)));
typedef float f32x4 __attribute__((ext_vector_type(4)));

#define GK 768   // inner K for both GEMMs
#define LN_EPS 1e-5f
#define NORM_EPS 1e-12f

// ---------------- async global->LDS helper ----------------
__device__ __forceinline__ void gl_lds16(const void* g, void* l) {
  __builtin_amdgcn_global_load_lds(
      (__attribute__((address_space(1))) uint32_t*)(uintptr_t)g,
      (__attribute__((address_space(3))) uint32_t*)(uintptr_t)l,
      16, 0, 0);
}

// ---------------- block reduce (2 values, 3 waves / 192 threads) ----------------
__device__ __forceinline__ void blockReduce2w3(float& s, float& ss, float* sm) {
  #pragma unroll
  for (int o = 32; o > 0; o >>= 1) {
    s  += __shfl_down(s, o, 64);
    ss += __shfl_down(ss, o, 64);
  }
  int wave = threadIdx.x >> 6, lane = threadIdx.x & 63;
  if (lane == 0) { sm[wave] = s; sm[3 + wave] = ss; }
  __syncthreads();
  s  = sm[0] + sm[1] + sm[2];
  ss = sm[3] + sm[4] + sm[5];
  __syncthreads();
}

// ---------------- 0: tiled transpose + fp32->bf16 ----------------
__global__ __launch_bounds__(256) void transpose_cvt(const float* __restrict__ w,
                                                     bf16* __restrict__ wt,
                                                     int R, int Ncols) {
  __shared__ float tile[32][33];
  int tx = threadIdx.x & 31, ty = threadIdx.x >> 5;
  int c0 = blockIdx.x * 32, r0 = blockIdx.y * 32;
  #pragma unroll
  for (int i = 0; i < 32; i += 8)
    tile[ty + i][tx] = w[(size_t)(r0 + ty + i) * Ncols + (c0 + tx)];
  __syncthreads();
  #pragma unroll
  for (int i = 0; i < 32; i += 8)
    wt[(size_t)(c0 + ty + i) * R + (r0 + tx)] = (bf16)tile[tx][ty + i];
}

// ---------------- 1: input LayerNorm -> bf16 (192 threads) ----------
__global__ __launch_bounds__(192) void ln_in_kernel(const float* __restrict__ x,
                                                    const float* __restrict__ g,
                                                    const float* __restrict__ b,
                                                    bf16* __restrict__ h) {
  __shared__ float sm[6];
  int row = blockIdx.x, t = threadIdx.x;
  const float* xr = x + (size_t)row * 768;
  float4 v = ((const float4*)xr)[t];
  float s  = v.x + v.y + v.z + v.w;
  float ss = v.x * v.x + v.y * v.y + v.z * v.z + v.w * v.w;
  blockReduce2w3(s, ss, sm);
  float mu  = s * (1.0f / 768.0f);
  float inv = rsqrtf(ss * (1.0f / 768.0f) - mu * mu + LN_EPS);
  float4 gg = ((const float4*)g)[t];
  float4 bb = ((const float4*)b)[t];
  bf16x4 o;
  o[0] = (bf16)((v.x - mu) * inv * gg.x + bb.x);
  o[1] = (bf16)((v.y - mu) * inv * gg.y + bb.y);
  o[2] = (bf16)((v.z - mu) * inv * gg.z + bb.z);
  o[3] = (bf16)((v.w - mu) * inv * gg.w + bb.w);
  ((bf16x4*)(h + (size_t)row * 768))[t] = o;
}

// ================= 256x256 8-phase bf16 GEMM (T2+T3+T4+T5) =================
// A[M][768] x Bt[N][768]^T -> C[M][N].  512 threads = 8 waves (2m x 4n).
// BK=64 -> 12 K-tiles -> 6 iterations x 2 tiles (buf0=even, buf1=odd).
// LDS 128 KiB. T2 swizzle: XOR byte-bits 4-6 with row-bits 0-2 (conflict-free,
// verified round 3). NO sched_barrier / manual lgkmcnt: the compiler schedules
// ds_read<->MFMA with fine-grained lgkmcnt (m141: order-pinning = 1.7x loss).
// Counted vmcnt(4) only at ph4/ph8 (ledger verified rounds 2-4).

#define SWZ(x) ((x) ^ ((((x) >> 7) & 7) << 4))

#define BAR __builtin_amdgcn_s_barrier()
#define VMC(n) asm volatile("s_waitcnt vmcnt(" #n ")" ::: "memory")
#define PRIO1 __builtin_amdgcn_s_setprio(1)
#define PRIO0 __builtin_amdgcn_s_setprio(0)

#define LDA1(base, mh, i, ks) \
  af[i][ks] = *(const bf16x8*)((base) + SWZ((wm * 128 + ((mh) * 4 + (i)) * 16 + llo) * 128 + (ks) * 64 + lhi * 16))
#define RD_A(base, mh) do { \
  LDA1(base, mh, 0, 0); LDA1(base, mh, 1, 0); LDA1(base, mh, 2, 0); LDA1(base, mh, 3, 0); \
  LDA1(base, mh, 0, 1); LDA1(base, mh, 1, 1); LDA1(base, mh, 2, 1); LDA1(base, mh, 3, 1); } while (0)

#define LDB1(base, n, ks) \
  bf[n][ks] = *(const bf16x8*)((base) + SWZ(((((n) >> 1) * 128 + wn * 32 + ((n) & 1) * 16 + llo) * 128 + (ks) * 64 + lhi * 16)))
#define RD_B01(base) do { LDB1(base, 0, 0); LDB1(base, 1, 0); LDB1(base, 0, 1); LDB1(base, 1, 1); } while (0)
#define RD_B23(base) do { LDB1(base, 2, 0); LDB1(base, 3, 0); LDB1(base, 2, 1); LDB1(base, 3, 1); } while (0)

#define MF1(mh, nh, i, jn, ks) \
  acc[(mh) * 4 + (i)][(nh) * 2 + (jn)] = __builtin_amdgcn_mfma_f32_16x16x32_bf16( \
      af[i][ks], bf[(nh) * 2 + (jn)][ks], acc[(mh) * 4 + (i)][(nh) * 2 + (jn)], 0, 0, 0)
#define MF8(mh, nh, ks) do { \
  MF1(mh, nh, 0, 0, ks); MF1(mh, nh, 0, 1, ks); MF1(mh, nh, 1, 0, ks); MF1(mh, nh, 1, 1, ks); \
  MF1(mh, nh, 2, 0, ks); MF1(mh, nh, 2, 1, ks); MF1(mh, nh, 3, 0, ks); MF1(mh, nh, 3, 1, ks); } while (0)
#define MFQ(mh, nh) do { PRIO1; MF8(mh, nh, 0); MF8(mh, nh, 1); PRIO0; } while (0)

#define STA(b, q, kt) gl_lds16(A + srcA[q] + (kt) * 64, &As_[b][(q) * 4096 + wave * 512])
#define STB(b, q, kt) gl_lds16(Bt + srcB[q] + (kt) * 64, &Bs_[b][(q) * 4096 + wave * 512])

template <bool OUT_BF16>
__global__ __launch_bounds__(512, 2) void gemm8p(const bf16* __restrict__ A,
                                                 const bf16* __restrict__ Bt,
                                                 void* __restrict__ Cv,
                                                 int Nn, int NBN) {
  __shared__ __align__(16) bf16 As_[2][16384];
  __shared__ __align__(16) bf16 Bs_[2][16384];
  const int tid = threadIdx.x;
  const int wave = tid >> 6, lane = tid & 63;
  const int llo = lane & 15, lhi = lane >> 4;
  const int wm = wave >> 2, wn = wave & 3;

  const int nwg = gridDim.x, bid = blockIdx.x;
  const int wg = (bid & 7) * (nwg >> 3) + (bid >> 3);
  const int rb = wg / NBN, cb = wg - rb * NBN;
  const int brow = rb * 256, bcol = cb * 256;

  // stage source element-offsets per chunk slot (involution pre-swizzle)
  uint32_t srcA[4], srcB[4];
  #pragma unroll
  for (int q = 0; q < 4; ++q) {
    int d = q * 8192 + tid * 16;          // dest byte offset within 32KB tile
    int a = SWZ(d);                       // logical byte offset
    int r = a >> 7, c = (a & 127) >> 1;   // logical row / bf16 col
    srcA[q] = (uint32_t)(brow + r) * GK + c;
    int nh = r >> 7, wnn = (r >> 5) & 3, r32 = r & 31;  // B row permutation
    srcB[q] = (uint32_t)(bcol + wnn * 64 + nh * 32 + r32) * GK + c;
  }

  f32x4 acc[8][4];
  #pragma unroll
  for (int m = 0; m < 8; ++m)
    #pragma unroll
    for (int n = 0; n < 4; ++n) acc[m][n] = (f32x4){0.f, 0.f, 0.f, 0.f};

  bf16x8 af[4][2], bf[4][2];
  const char* As0 = (const char*)&As_[0][0];
  const char* As1 = (const char*)&As_[1][0];
  const char* Bs0 = (const char*)&Bs_[0][0];
  const char* Bs1 = (const char*)&Bs_[1][0];

  // -------- prologue: tile0 full (8 chunks), tile1 partial (4); keep 4 in flight
  STA(0, 0, 0); STA(0, 1, 0); STA(0, 2, 0); STA(0, 3, 0);
  STB(0, 0, 0); STB(0, 1, 0); STB(0, 2, 0); STB(0, 3, 0);
  STA(1, 0, 1); STA(1, 2, 1); STB(1, 0, 1); STB(1, 1, 1);
  VMC(4);
  BAR;

  for (int j = 0; j < 6; ++j) {
    const int t1 = 2 * j + 1, t2 = 2 * j + 2, t3 = 2 * j + 3;
    // ---- ph1: reads A-mh0 + all B of even tile; MFMA mh0 x n01
    RD_A(As0, 0); RD_B01(Bs0); RD_B23(Bs0);
    STA(1, 1, t1); STA(1, 3, t1);
    BAR;
    MFQ(0, 0);
    BAR;
    // ---- ph2: read-free; MFMA mh0 x n23
    STB(1, 2, t1); STB(1, 3, t1);
    BAR;
    MFQ(0, 1);
    BAR;
    // ---- ph3: reads A-mh1; MFMA mh1 x n01
    RD_A(As0, 1);
    STA(0, 0, t2); STA(0, 2, t2);
    BAR;
    MFQ(1, 0);
    BAR;
    // ---- ph4: read-free; MFMA mh1 x n23; counted vmcnt for odd tile
    STB(0, 0, t2); STB(0, 1, t2);
    BAR;
    MFQ(1, 1);
    VMC(4);
    BAR;
    // ---- ph5..8: odd tile from buf1
    RD_A(As1, 0); RD_B01(Bs1); RD_B23(Bs1);
    STA(0, 1, t2); STA(0, 3, t2);
    BAR;
    MFQ(0, 0);
    BAR;
    STB(0, 2, t2); STB(0, 3, t2);
    BAR;
    MFQ(0, 1);
    BAR;
    RD_A(As1, 1);
    STA(1, 0, t3); STA(1, 2, t3);
    BAR;
    MFQ(1, 0);
    BAR;
    STB(1, 0, t3); STB(1, 1, t3);
    BAR;
    MFQ(1, 1);
    VMC(4);
    BAR;
  }

  // -------- epilogue: C write
  #pragma unroll
  for (int m = 0; m < 8; ++m) {
    #pragma unroll
    for (int n = 0; n < 4; ++n) {
      int row = brow + wm * 128 + m * 16 + lhi * 4;
      int col = bcol + wn * 64 + n * 16 + llo;
      #pragma unroll
      for (int r2 = 0; r2 < 4; ++r2) {
        if (OUT_BF16)
          ((bf16*)Cv)[(size_t)(row + r2) * Nn + col] = (bf16)acc[m][n][r2];
        else
          ((float*)Cv)[(size_t)(row + r2) * Nn + col] = acc[m][n][r2];
      }
    }
  }
}

// ---------------- 3a: kv partial sums, k-norm computed inline ----------------
__global__ __launch_bounds__(256) void kv_partial(const bf16* __restrict__ qkv,
                                                  float* __restrict__ kvp) {
  __shared__ float sm[4][768];
  int b = blockIdx.x >> 5, chunk = blockIdx.x & 31;
  int wave = threadIdx.x >> 6, lane = threadIdx.x & 63;
  const bf16* base = qkv + ((size_t)(b * 4096 + chunk * 128 + wave * 32)) * 2304;
  float acc[3][4] = {};
  for (int i = 0; i < 32; ++i) {
    const bf16* kr = base + (size_t)i * 2304 + 768;
    const bf16* vr = kr + 768;
    bf16x4 k4[3], v4[3];
    #pragma unroll
    for (int c = 0; c < 3; ++c) {
      k4[c] = *(const bf16x4*)(kr + c * 256 + lane * 4);
      v4[c] = *(const bf16x4*)(vr + c * 256 + lane * 4);
    }
    float ssk = 0.f;
    #pragma unroll
    for (int c = 0; c < 3; ++c)
      #pragma unroll
      for (int j = 0; j < 4; ++j) { float kf = (float)k4[c][j]; ssk += kf * kf; }
    #pragma unroll
    for (int off = 32; off > 0; off >>= 1) ssk += __shfl_xor(ssk, off, 64);
    float wi = 1.0f / fmaxf(sqrtf(ssk), NORM_EPS);
    #pragma unroll
    for (int c = 0; c < 3; ++c)
      #pragma unroll
      for (int j = 0; j < 4; ++j)
        acc[c][j] += (float)k4[c][j] * (float)v4[c][j] * wi;
  }
  #pragma unroll
  for (int c = 0; c < 3; ++c)
    #pragma unroll
    for (int j = 0; j < 4; ++j)
      sm[wave][c * 256 + lane * 4 + j] = acc[c][j];
  __syncthreads();
  int t = threadIdx.x;
  #pragma unroll
  for (int c = 0; c < 3; ++c) {
    int e = c * 256 + t;
    kvp[(size_t)blockIdx.x * 768 + e] = sm[0][e] + sm[1][e] + sm[2][e] + sm[3][e];
  }
}

// ---------------- 3b: reduce 32 partials -> kv[8][768] ----------------
__global__ __launch_bounds__(256) void kv_reduce(const float* __restrict__ kvp,
                                                 float* __restrict__ kv) {
  int i = blockIdx.x * 256 + threadIdx.x;
  int b = i / 768, e = i - b * 768;
  float s = 0.f;
  #pragma unroll
  for (int c = 0; c < 32; ++c) s += kvp[(size_t)(b * 32 + c) * 768 + e];
  kv[i] = s;
}

// ---------------- 4: attn = phi_q * kv (q-norm inline), LN over E -> bf16 ----
__global__ __launch_bounds__(192) void attn_ln_kernel(const bf16* __restrict__ qkv,
                                                      const float* __restrict__ kv,
                                                      const float* __restrict__ g,
                                                      const float* __restrict__ b,
                                                      bf16* __restrict__ a) {
  __shared__ float sm[6];
  int row = blockIdx.x, t = threadIdx.x;
  int bt = row >> 12;
  const bf16* qr = qkv + (size_t)row * 2304;
  bf16x4 q4 = ((const bf16x4*)qr)[t];
  float q0 = (float)q4[0], q1 = (float)q4[1], q2 = (float)q4[2], q3 = (float)q4[3];
  float sq = q0 * q0 + q1 * q1 + q2 * q2 + q3 * q3, dummy = 0.f;
  blockReduce2w3(sq, dummy, sm);
  float iq = 1.0f / fmaxf(sqrtf(sq), NORM_EPS);
  float4 kv4 = ((const float4*)(kv + bt * 768))[t];
  float4 av;
  av.x = q0 * iq * kv4.x;
  av.y = q1 * iq * kv4.y;
  av.z = q2 * iq * kv4.z;
  av.w = q3 * iq * kv4.w;
  float s  = av.x + av.y + av.z + av.w;
  float ss = av.x * av.x + av.y * av.y + av.z * av.z + av.w * av.w;
  blockReduce2w3(s, ss, sm);
  float mu  = s * (1.0f / 768.0f);
  float inv = rsqrtf(ss * (1.0f / 768.0f) - mu * mu + LN_EPS);
  float4 gg = ((const float4*)g)[t];
  float4 bb = ((const float4*)b)[t];
  bf16x4 o;
  o[0] = (bf16)((av.x - mu) * inv * gg.x + bb.x);
  o[1] = (bf16)((av.y - mu) * inv * gg.y + bb.y);
  o[2] = (bf16)((av.z - mu) * inv * gg.z + bb.z);
  o[3] = (bf16)((av.w - mu) * inv * gg.w + bb.w);
  ((bf16x4*)(a + (size_t)row * 768))[t] = o;
}

// ---------------- launcher ----------------
extern "C" void kernel_launch(void* const* d_in, const int* in_sizes, int n_in,
                              void* d_out, int out_size, void* d_ws, size_t ws_size,
                              hipStream_t stream) {
  const float* x      = (const float*)d_in[0];
  const float* w_qkv  = (const float*)d_in[1];
  const float* w_proj = (const float*)d_in[2];
  const float* g_in   = (const float*)d_in[3];
  const float* b_in   = (const float*)d_in[4];
  const float* g_out  = (const float*)d_in[5];
  const float* b_out  = (const float*)d_in[6];

  char* ws = (char*)d_ws;
  bf16*  wqkvt  = (bf16*)(ws);                              // [2304][768] bf16
  bf16*  wprojt = (bf16*)(ws + 3538944);                    // [768][768]  bf16
  bf16*  h      = (bf16*)(ws + 4718592);                    // [32768][768] bf16 (reused as 'a')
  bf16*  qkv    = (bf16*)(ws + 55050240);                   // [32768][2304] bf16
  float* kvp    = (float*)(ws + 206045184);                 // [8*32][768]
  float* kv     = (float*)(ws + 206831616);                 // [8][768]

  transpose_cvt<<<dim3(2304 / 32, 768 / 32), 256, 0, stream>>>(w_qkv, wqkvt, 768, 2304);
  transpose_cvt<<<dim3(768 / 32, 768 / 32), 256, 0, stream>>>(w_proj, wprojt, 768, 768);
  ln_in_kernel<<<32768, 192, 0, stream>>>(x, g_in, b_in, h);
  gemm8p<true><<<128 * 9, 512, 0, stream>>>(h, wqkvt, (void*)qkv, 2304, 9);
  kv_partial<<<256, 256, 0, stream>>>(qkv, kvp);
  kv_reduce<<<24, 256, 0, stream>>>(kvp, kv);
  attn_ln_kernel<<<32768, 192, 0, stream>>>(qkv, kv, g_out, b_out, h);
  gemm8p<false><<<128 * 3, 512, 0, stream>>>(h, wprojt, d_out, 768, 3);
}

// Round 8
// 268.850 us; speedup vs baseline: 2.2819x; 1.0874x over previous
//
#include <hip/hip_runtime.h>
#include <hip/hip_bf16.h>
#include <cstdint>

typedef __bf16 bf16;
typedef __bf16 bf16x4 __attribute__((ext_vector_type(4)));
typedef __bf16 bf16x8 __attribute__((ext_vector_type(8)));
typedef float f32x4 __attribute__((ext_vector_type(4)));

#define GK 768   // inner K for both GEMMs
#define LN_EPS 1e-5f
#define NORM_EPS 1e-12f

// ---------------- async global->LDS helper ----------------
__device__ __forceinline__ void gl_lds16(const void* g, void* l) {
  __builtin_amdgcn_global_load_lds(
      (__attribute__((address_space(1))) uint32_t*)(uintptr_t)g,
      (__attribute__((address_space(3))) uint32_t*)(uintptr_t)l,
      16, 0, 0);
}

// ---------------- block reduce (2 values, 3 waves / 192 threads) ----------------
__device__ __forceinline__ void blockReduce2w3(float& s, float& ss, float* sm) {
  #pragma unroll
  for (int o = 32; o > 0; o >>= 1) {
    s  += __shfl_down(s, o, 64);
    ss += __shfl_down(ss, o, 64);
  }
  int wave = threadIdx.x >> 6, lane = threadIdx.x & 63;
  if (lane == 0) { sm[wave] = s; sm[3 + wave] = ss; }
  __syncthreads();
  s  = sm[0] + sm[1] + sm[2];
  ss = sm[3] + sm[4] + sm[5];
  __syncthreads();
}

// ---------------- 0: tiled transpose + fp32->bf16 ----------------
__global__ __launch_bounds__(256) void transpose_cvt(const float* __restrict__ w,
                                                     bf16* __restrict__ wt,
                                                     int R, int Ncols) {
  __shared__ float tile[32][33];
  int tx = threadIdx.x & 31, ty = threadIdx.x >> 5;
  int c0 = blockIdx.x * 32, r0 = blockIdx.y * 32;
  #pragma unroll
  for (int i = 0; i < 32; i += 8)
    tile[ty + i][tx] = w[(size_t)(r0 + ty + i) * Ncols + (c0 + tx)];
  __syncthreads();
  #pragma unroll
  for (int i = 0; i < 32; i += 8)
    wt[(size_t)(c0 + ty + i) * R + (r0 + tx)] = (bf16)tile[tx][ty + i];
}

// ---------------- 1: input LayerNorm -> bf16 (192 threads) ----------
__global__ __launch_bounds__(192) void ln_in_kernel(const float* __restrict__ x,
                                                    const float* __restrict__ g,
                                                    const float* __restrict__ b,
                                                    bf16* __restrict__ h) {
  __shared__ float sm[6];
  int row = blockIdx.x, t = threadIdx.x;
  const float* xr = x + (size_t)row * 768;
  float4 v = ((const float4*)xr)[t];
  float s  = v.x + v.y + v.z + v.w;
  float ss = v.x * v.x + v.y * v.y + v.z * v.z + v.w * v.w;
  blockReduce2w3(s, ss, sm);
  float mu  = s * (1.0f / 768.0f);
  float inv = rsqrtf(ss * (1.0f / 768.0f) - mu * mu + LN_EPS);
  float4 gg = ((const float4*)g)[t];
  float4 bb = ((const float4*)b)[t];
  bf16x4 o;
  o[0] = (bf16)((v.x - mu) * inv * gg.x + bb.x);
  o[1] = (bf16)((v.y - mu) * inv * gg.y + bb.y);
  o[2] = (bf16)((v.z - mu) * inv * gg.z + bb.z);
  o[3] = (bf16)((v.w - mu) * inv * gg.w + bb.w);
  ((bf16x4*)(h + (size_t)row * 768))[t] = o;
}

// ================= 128x128 bf16 GEMM, 2 blocks/CU (T2+T4+T5+m114) ==========
// A[M][768] x Bt[N][768]^T -> C[M][N].  256 threads = 4 waves (2m x 2n),
// wave = 64x64 (4x4 frags). BK=64 -> 12 K-tiles. LDS 64 KiB (2 bufs x 32KB)
// -> 2 blocks/CU: inter-block overlap hides barrier/lgkm/vmcnt stalls (m114).
// Counted vmcnt(8): stage tile j+2 after the barrier, never drain in loop.
// T2 swizzle: XOR byte-bits 4-6 with row-bits 0-2 (involution, both sides).

#define SWZ(x) ((x) ^ ((((x) >> 7) & 7) << 4))

#define BAR __builtin_amdgcn_s_barrier()
#define VMC(n) asm volatile("s_waitcnt vmcnt(" #n ")" ::: "memory")
#define PRIO1 __builtin_amdgcn_s_setprio(1)
#define PRIO0 __builtin_amdgcn_s_setprio(0)

#define LDA1(base, i, ks) \
  af[i][ks] = *(const bf16x8*)((base) + SWZ((wm * 64 + (i) * 16 + llo) * 128 + (ks) * 64 + lhi * 16))
#define LDB1(base, j, ks) \
  bf[j][ks] = *(const bf16x8*)((base) + SWZ((wn * 64 + (j) * 16 + llo) * 128 + (ks) * 64 + lhi * 16))
#define RDALL(Ab, Bb) do { \
  LDA1(Ab, 0, 0); LDA1(Ab, 1, 0); LDA1(Ab, 2, 0); LDA1(Ab, 3, 0); \
  LDB1(Bb, 0, 0); LDB1(Bb, 1, 0); LDB1(Bb, 2, 0); LDB1(Bb, 3, 0); \
  LDA1(Ab, 0, 1); LDA1(Ab, 1, 1); LDA1(Ab, 2, 1); LDA1(Ab, 3, 1); \
  LDB1(Bb, 0, 1); LDB1(Bb, 1, 1); LDB1(Bb, 2, 1); LDB1(Bb, 3, 1); } while (0)

#define MF1(m, n, ks) \
  acc[m][n] = __builtin_amdgcn_mfma_f32_16x16x32_bf16(af[m][ks], bf[n][ks], acc[m][n], 0, 0, 0)
#define MFALL do { PRIO1; \
  MF1(0,0,0); MF1(0,1,0); MF1(0,2,0); MF1(0,3,0); \
  MF1(1,0,0); MF1(1,1,0); MF1(1,2,0); MF1(1,3,0); \
  MF1(2,0,0); MF1(2,1,0); MF1(2,2,0); MF1(2,3,0); \
  MF1(3,0,0); MF1(3,1,0); MF1(3,2,0); MF1(3,3,0); \
  MF1(0,0,1); MF1(0,1,1); MF1(0,2,1); MF1(0,3,1); \
  MF1(1,0,1); MF1(1,1,1); MF1(1,2,1); MF1(1,3,1); \
  MF1(2,0,1); MF1(2,1,1); MF1(2,2,1); MF1(2,3,1); \
  MF1(3,0,1); MF1(3,1,1); MF1(3,2,1); MF1(3,3,1); \
  PRIO0; } while (0)

#define STA2(b, q, t) gl_lds16(A + srcA[q] + (t) * 64, &As_[b][(q) * 2048 + wave * 512])
#define STB2(b, q, t) gl_lds16(Bt + srcB[q] + (t) * 64, &Bs_[b][(q) * 2048 + wave * 512])
#define STAGE(b, t) do { \
  STA2(b, 0, t); STA2(b, 1, t); STA2(b, 2, t); STA2(b, 3, t); \
  STB2(b, 0, t); STB2(b, 1, t); STB2(b, 2, t); STB2(b, 3, t); } while (0)

template <bool OUT_BF16>
__global__ __launch_bounds__(256, 2) void gemm128(const bf16* __restrict__ A,
                                                  const bf16* __restrict__ Bt,
                                                  void* __restrict__ Cv,
                                                  int Nn, int NBN) {
  __shared__ __align__(16) bf16 As_[2][8192];   // 16KB per buf
  __shared__ __align__(16) bf16 Bs_[2][8192];
  const int tid = threadIdx.x;
  const int wave = tid >> 6, lane = tid & 63;
  const int llo = lane & 15, lhi = lane >> 4;
  const int wm = wave >> 1, wn = wave & 1;

  const int nwg = gridDim.x, bid = blockIdx.x;
  const int wg = (bid & 7) * (nwg >> 3) + (bid >> 3);
  const int rb = wg / NBN, cb = wg - rb * NBN;
  const int brow = rb * 128, bcol = cb * 128;

  // stage source element-offsets per chunk (involution pre-swizzle)
  uint32_t srcA[4], srcB[4];
  #pragma unroll
  for (int q = 0; q < 4; ++q) {
    int d = q * 4096 + tid * 16;          // dest byte offset within 16KB tile
    int a = SWZ(d);                       // logical byte offset
    int r = a >> 7, c = (a & 127) >> 1;   // logical row / bf16 col
    srcA[q] = (uint32_t)(brow + r) * GK + c;
    srcB[q] = (uint32_t)(bcol + r) * GK + c;
  }

  f32x4 acc[4][4];
  #pragma unroll
  for (int m = 0; m < 4; ++m)
    #pragma unroll
    for (int n = 0; n < 4; ++n) acc[m][n] = (f32x4){0.f, 0.f, 0.f, 0.f};

  bf16x8 af[4][2], bf[4][2];
  const char* As0 = (const char*)&As_[0][0];
  const char* As1 = (const char*)&As_[1][0];
  const char* Bs0 = (const char*)&Bs_[0][0];
  const char* Bs1 = (const char*)&Bs_[1][0];

  // prologue: stage tiles 0,1; wait tile0 (8 oldest), tile1 may stay in flight
  STAGE(0, 0);
  STAGE(1, 1);
  VMC(8);
  BAR;

  #pragma unroll
  for (int j = 0; j < 5; ++j) {
    // even tile 2j from buf0
    RDALL(As0, Bs0);
    MFALL;
    BAR;                       // all waves done reading buf0
    STAGE(0, 2 * j + 2);       // overwrite buf0 with tile 2j+2
    VMC(8);                    // tile 2j+1 (staged earlier) fully landed
    BAR;
    // odd tile 2j+1 from buf1
    RDALL(As1, Bs1);
    MFALL;
    BAR;
    STAGE(1, 2 * j + 3);
    VMC(8);                    // tile 2j+2 landed
    BAR;
  }
  // tile 10 (buf0); no more staging
  RDALL(As0, Bs0);
  MFALL;
  BAR;
  VMC(0);                      // tile 11 landed
  BAR;
  // tile 11 (buf1)
  RDALL(As1, Bs1);
  MFALL;

  // epilogue: C write
  #pragma unroll
  for (int m = 0; m < 4; ++m) {
    #pragma unroll
    for (int n = 0; n < 4; ++n) {
      int row = brow + wm * 64 + m * 16 + lhi * 4;
      int col = bcol + wn * 64 + n * 16 + llo;
      #pragma unroll
      for (int r2 = 0; r2 < 4; ++r2) {
        if (OUT_BF16)
          ((bf16*)Cv)[(size_t)(row + r2) * Nn + col] = (bf16)acc[m][n][r2];
        else
          ((float*)Cv)[(size_t)(row + r2) * Nn + col] = acc[m][n][r2];
      }
    }
  }
}

// ---------------- 3a: kv partial sums, k-norm computed inline ----------------
__global__ __launch_bounds__(256) void kv_partial(const bf16* __restrict__ qkv,
                                                  float* __restrict__ kvp) {
  __shared__ float sm[4][768];
  int b = blockIdx.x >> 5, chunk = blockIdx.x & 31;
  int wave = threadIdx.x >> 6, lane = threadIdx.x & 63;
  const bf16* base = qkv + ((size_t)(b * 4096 + chunk * 128 + wave * 32)) * 2304;
  float acc[3][4] = {};
  for (int i = 0; i < 32; ++i) {
    const bf16* kr = base + (size_t)i * 2304 + 768;
    const bf16* vr = kr + 768;
    bf16x4 k4[3], v4[3];
    #pragma unroll
    for (int c = 0; c < 3; ++c) {
      k4[c] = *(const bf16x4*)(kr + c * 256 + lane * 4);
      v4[c] = *(const bf16x4*)(vr + c * 256 + lane * 4);
    }
    float ssk = 0.f;
    #pragma unroll
    for (int c = 0; c < 3; ++c)
      #pragma unroll
      for (int j = 0; j < 4; ++j) { float kf = (float)k4[c][j]; ssk += kf * kf; }
    #pragma unroll
    for (int off = 32; off > 0; off >>= 1) ssk += __shfl_xor(ssk, off, 64);
    float wi = 1.0f / fmaxf(sqrtf(ssk), NORM_EPS);
    #pragma unroll
    for (int c = 0; c < 3; ++c)
      #pragma unroll
      for (int j = 0; j < 4; ++j)
        acc[c][j] += (float)k4[c][j] * (float)v4[c][j] * wi;
  }
  #pragma unroll
  for (int c = 0; c < 3; ++c)
    #pragma unroll
    for (int j = 0; j < 4; ++j)
      sm[wave][c * 256 + lane * 4 + j] = acc[c][j];
  __syncthreads();
  int t = threadIdx.x;
  #pragma unroll
  for (int c = 0; c < 3; ++c) {
    int e = c * 256 + t;
    kvp[(size_t)blockIdx.x * 768 + e] = sm[0][e] + sm[1][e] + sm[2][e] + sm[3][e];
  }
}

// ---------------- 3b: reduce 32 partials -> kv[8][768] ----------------
__global__ __launch_bounds__(256) void kv_reduce(const float* __restrict__ kvp,
                                                 float* __restrict__ kv) {
  int i = blockIdx.x * 256 + threadIdx.x;
  int b = i / 768, e = i - b * 768;
  float s = 0.f;
  #pragma unroll
  for (int c = 0; c < 32; ++c) s += kvp[(size_t)(b * 32 + c) * 768 + e];
  kv[i] = s;
}

// ---------------- 4: attn = phi_q * kv (q-norm inline), LN over E -> bf16 ----
__global__ __launch_bounds__(192) void attn_ln_kernel(const bf16* __restrict__ qkv,
                                                      const float* __restrict__ kv,
                                                      const float* __restrict__ g,
                                                      const float* __restrict__ b,
                                                      bf16* __restrict__ a) {
  __shared__ float sm[6];
  int row = blockIdx.x, t = threadIdx.x;
  int bt = row >> 12;
  const bf16* qr = qkv + (size_t)row * 2304;
  bf16x4 q4 = ((const bf16x4*)qr)[t];
  float q0 = (float)q4[0], q1 = (float)q4[1], q2 = (float)q4[2], q3 = (float)q4[3];
  float sq = q0 * q0 + q1 * q1 + q2 * q2 + q3 * q3, dummy = 0.f;
  blockReduce2w3(sq, dummy, sm);
  float iq = 1.0f / fmaxf(sqrtf(sq), NORM_EPS);
  float4 kv4 = ((const float4*)(kv + bt * 768))[t];
  float4 av;
  av.x = q0 * iq * kv4.x;
  av.y = q1 * iq * kv4.y;
  av.z = q2 * iq * kv4.z;
  av.w = q3 * iq * kv4.w;
  float s  = av.x + av.y + av.z + av.w;
  float ss = av.x * av.x + av.y * av.y + av.z * av.z + av.w * av.w;
  blockReduce2w3(s, ss, sm);
  float mu  = s * (1.0f / 768.0f);
  float inv = rsqrtf(ss * (1.0f / 768.0f) - mu * mu + LN_EPS);
  float4 gg = ((const float4*)g)[t];
  float4 bb = ((const float4*)b)[t];
  bf16x4 o;
  o[0] = (bf16)((av.x - mu) * inv * gg.x + bb.x);
  o[1] = (bf16)((av.y - mu) * inv * gg.y + bb.y);
  o[2] = (bf16)((av.z - mu) * inv * gg.z + bb.z);
  o[3] = (bf16)((av.w - mu) * inv * gg.w + bb.w);
  ((bf16x4*)(a + (size_t)row * 768))[t] = o;
}

// ---------------- launcher ----------------
extern "C" void kernel_launch(void* const* d_in, const int* in_sizes, int n_in,
                              void* d_out, int out_size, void* d_ws, size_t ws_size,
                              hipStream_t stream) {
  const float* x      = (const float*)d_in[0];
  const float* w_qkv  = (const float*)d_in[1];
  const float* w_proj = (const float*)d_in[2];
  const float* g_in   = (const float*)d_in[3];
  const float* b_in   = (const float*)d_in[4];
  const float* g_out  = (const float*)d_in[5];
  const float* b_out  = (const float*)d_in[6];

  char* ws = (char*)d_ws;
  bf16*  wqkvt  = (bf16*)(ws);                              // [2304][768] bf16
  bf16*  wprojt = (bf16*)(ws + 3538944);                    // [768][768]  bf16
  bf16*  h      = (bf16*)(ws + 4718592);                    // [32768][768] bf16 (reused as 'a')
  bf16*  qkv    = (bf16*)(ws + 55050240);                   // [32768][2304] bf16
  float* kvp    = (float*)(ws + 206045184);                 // [8*32][768]
  float* kv     = (float*)(ws + 206831616);                 // [8][768]

  transpose_cvt<<<dim3(2304 / 32, 768 / 32), 256, 0, stream>>>(w_qkv, wqkvt, 768, 2304);
  transpose_cvt<<<dim3(768 / 32, 768 / 32), 256, 0, stream>>>(w_proj, wprojt, 768, 768);
  ln_in_kernel<<<32768, 192, 0, stream>>>(x, g_in, b_in, h);
  gemm128<true><<<256 * 18, 256, 0, stream>>>(h, wqkvt, (void*)qkv, 2304, 18);
  kv_partial<<<256, 256, 0, stream>>>(qkv, kvp);
  kv_reduce<<<24, 256, 0, stream>>>(kvp, kv);
  attn_ln_kernel<<<32768, 192, 0, stream>>>(qkv, kv, g_out, b_out, h);
  gemm128<false><<<256 * 6, 256, 0, stream>>>(h, wprojt, d_out, 768, 6);
}